// Round 9
// baseline (214.783 us; speedup 1.0000x reference)
//
#include <hip/hip_runtime.h>
#include <hip/hip_bf16.h>
#include <stdint.h>

typedef unsigned short u16;
typedef short bf16x8 __attribute__((ext_vector_type(8)));
typedef float f32x4 __attribute__((ext_vector_type(4)));

#define DEVI static __device__ __forceinline__

#if __has_builtin(__builtin_amdgcn_exp2f)
#define EXP2F(x) __builtin_amdgcn_exp2f(x)
#else
#define EXP2F(x) exp2f(x)
#endif

DEVI u16 f2bf(float f) {
  union { float f; uint32_t u; } v; v.f = f;
  uint32_t u = v.u;
  u += 0x7fffu + ((u >> 16) & 1u);   // round-to-nearest-even
  return (u16)(u >> 16);
}
DEVI uint32_t pk2bf(float lo, float hi) {
  __hip_bfloat162 h = __float22bfloat162_rn(float2{lo, hi});
  union { __hip_bfloat162 h; uint32_t u; } v; v.h = h; return v.u;
}

DEVI void async16(const void* g, const void* l) {
  __builtin_amdgcn_global_load_lds(
      (const __attribute__((address_space(1))) void*)g,
      (__attribute__((address_space(3))) void*)l, 16, 0, 0);
}

DEVI f32x4 mfma16(bf16x8 a, bf16x8 b, f32x4 c) {
  return __builtin_amdgcn_mfma_f32_16x16x32_bf16(a, b, c, 0, 0, 0);
}

// ---------------------------------------------------------------- constants
// B=2, S=2048, H=1024, NH=16, D=64, M=B*S=4096
// log2(e)/sqrt(64): folded into Q at the qkv epilogue
#define CSC 0.18033688011112042f

// ------------------------------------------------- kernel 1: fp32 -> bf16 x
__global__ void convx(const float* __restrict__ q, const float* __restrict__ k,
                      const float* __restrict__ v, u16* __restrict__ out) {
  const int z = blockIdx.y;
  const float* src = (z == 0) ? q : (z == 1) ? k : v;
  const int i = (blockIdx.x * 256 + threadIdx.x) * 4;
  float4 f = *(const float4*)(src + i);
  ushort4 o;
  o.x = f2bf(f.x); o.y = f2bf(f.y); o.z = f2bf(f.z); o.w = f2bf(f.w);
  *(ushort4*)(out + (size_t)z * 4194304 + i) = o;
}

// ----------------------------------- kernel 2: W[k][n] -> Wt[n][k] in bf16
__global__ void transw(const float* __restrict__ Wq, const float* __restrict__ Wk,
                       const float* __restrict__ Wv, const float* __restrict__ Wo,
                       u16* __restrict__ WT) {
  __shared__ u16 tile[64 * 68];
  const int z = blockIdx.z;
  const float* W = (z == 0) ? Wq : (z == 1) ? Wk : (z == 2) ? Wv : Wo;
  u16* out = WT + (size_t)z * 1048576;
  const int R0 = blockIdx.y * 64, C0 = blockIdx.x * 64;
  const int t = threadIdx.x;
#pragma unroll
  for (int it = 0; it < 16; ++it) {
    int j = it * 256 + t;
    int r = j >> 6, c = j & 63;
    tile[r * 68 + c] = f2bf(W[(size_t)(R0 + r) * 1024 + C0 + c]);
  }
  __syncthreads();
#pragma unroll
  for (int it = 0; it < 16; ++it) {
    int j = it * 256 + t;
    int c = j >> 6, r = j & 63;
    out[(size_t)(C0 + c) * 1024 + R0 + r] = tile[r * 68 + c];
  }
}

// -------------------------------------------------- fused QKV projection GEMM
// BK=64, 16 k-iters, uniform C^T orientation (regs = n = d-dim) for ALL z.
// Epilogue bounces acc through LDS so every global store is a 256B-contiguous
// run (full-line coverage). z=0: Q natural [b,s,1024] pre-scaled by CSC;
// z=1: K natural [b,s,1024]; z=2: V^T [b,h,d,s].
// XCD swizzle: 1-D grid of 256 tiles, m_tile = T&31 -> same-A-stripe blocks
// share an XCD (xcd = T%8 = m%8); per-XCD: 4 A-stripes + full B = 3MB < 4MB L2.
__global__ __launch_bounds__(256, 3)
void qkv_gemm(const u16* __restrict__ XB, const u16* __restrict__ WT,
              const float* __restrict__ bq, const float* __restrict__ bk,
              const float* __restrict__ bv,
              u16* __restrict__ QN, u16* __restrict__ KN, u16* __restrict__ VT) {
  __shared__ u16 smem[16896];          // lA(8192) + lB(8192); reused as 128x132 bounce
  u16* lA = smem;
  u16* lB = smem + 8192;
  const int z = blockIdx.y;
  const u16* A  = XB + (size_t)z * 4194304;
  const u16* Bt = WT + (size_t)z * 1048576;
  const float* bias = (z == 0) ? bq : (z == 1) ? bk : bv;
  const int T = blockIdx.x;
  const int m0 = (T & 31) * 128, n0 = (T >> 5) * 128;
  const int t = threadIdx.x, lane = t & 63, w = t >> 6;
  const int quad = lane >> 4, l16 = lane & 15;
  const int wm = (w & 1) * 64, wn = (w >> 1) * 64;

  f32x4 acc[4][4] = {};
  for (int kt = 0; kt < 16; ++kt) {
    const int k0 = kt * 64;
#pragma unroll
    for (int it = 0; it < 4; ++it) {
      int i = it * 256 + t;
      int r = i >> 3, cc = i & 7, c = cc ^ (r & 7);
      async16(A + (size_t)(m0 + r) * 1024 + k0 + c * 8, &lA[i * 8]);
      async16(Bt + (size_t)(n0 + r) * 1024 + k0 + c * 8, &lB[i * 8]);
    }
    __syncthreads();
#pragma unroll
    for (int ks = 0; ks < 2; ++ks) {
      bf16x8 af[4], bfr[4];
#pragma unroll
      for (int rt = 0; rt < 4; ++rt) {
        int row = wm + rt * 16 + l16;
        af[rt] = *(const bf16x8*)&lA[row * 64 + ((ks * 4 + quad) ^ (row & 7)) * 8];
      }
#pragma unroll
      for (int ct = 0; ct < 4; ++ct) {
        int row = wn + ct * 16 + l16;
        bfr[ct] = *(const bf16x8*)&lB[row * 64 + ((ks * 4 + quad) ^ (row & 7)) * 8];
      }
#pragma unroll
      for (int rt = 0; rt < 4; ++rt)
#pragma unroll
        for (int ct = 0; ct < 4; ++ct)
          acc[rt][ct] = mfma16(bfr[ct], af[rt], acc[rt][ct]);  // C^T: regs = d
    }
    __syncthreads();
  }

  // ---- epilogue via LDS bounce (all waves past final barrier; smem reusable)
  if (z < 2) {
    const float scl = (z == 0) ? CSC : 1.0f;
    // acc -> smem[s][132 + d]  (s-local = wm+rt*16+l16, d-local = wn+ct*16+quad*4)
#pragma unroll
    for (int rt = 0; rt < 4; ++rt) {
      int sl = wm + rt * 16 + l16;
#pragma unroll
      for (int ct = 0; ct < 4; ++ct) {
        int nb = wn + ct * 16 + quad * 4;
        float4 b4 = *(const float4*)&bias[n0 + nb];
        ushort4 pk;
        pk.x = f2bf((acc[rt][ct][0] + b4.x) * scl);
        pk.y = f2bf((acc[rt][ct][1] + b4.y) * scl);
        pk.z = f2bf((acc[rt][ct][2] + b4.z) * scl);
        pk.w = f2bf((acc[rt][ct][3] + b4.w) * scl);
        *(ushort4*)&smem[sl * 132 + nb] = pk;
      }
    }
    __syncthreads();
    // coalesced store: natural [4096][1024]; 256B-contiguous per 16 lanes
    u16* out = (z == 0) ? QN : KN;
#pragma unroll
    for (int p = 0; p < 8; ++p) {
      int idx = p * 256 + t;
      int row = idx >> 4, chunk = idx & 15;
      *(bf16x8*)&out[(size_t)(m0 + row) * 1024 + n0 + chunk * 8] =
          *(const bf16x8*)&smem[row * 132 + chunk * 8];
    }
  } else {
    // acc -> smem[d][132 + s] (transpose via scalar LDS writes)
#pragma unroll
    for (int rt = 0; rt < 4; ++rt) {
      int sl = wm + rt * 16 + l16;
#pragma unroll
      for (int ct = 0; ct < 4; ++ct) {
        int nb = wn + ct * 16 + quad * 4;
        float4 b4 = *(const float4*)&bias[n0 + nb];
        smem[(nb + 0) * 132 + sl] = f2bf(acc[rt][ct][0] + b4.x);
        smem[(nb + 1) * 132 + sl] = f2bf(acc[rt][ct][1] + b4.y);
        smem[(nb + 2) * 132 + sl] = f2bf(acc[rt][ct][2] + b4.z);
        smem[(nb + 3) * 132 + sl] = f2bf(acc[rt][ct][3] + b4.w);
      }
    }
    __syncthreads();
    // coalesced store: VT[b,h,d,s]; 256B-contiguous per 16 lanes
    const int bb = m0 >> 11, sb = m0 & 2047;
#pragma unroll
    for (int p = 0; p < 8; ++p) {
      int idx = p * 256 + t;
      int dl = idx >> 4, chunk = idx & 15;
      int ncol = n0 + dl, hh = ncol >> 6, dd = ncol & 63;
      *(bf16x8*)&VT[((size_t)((bb * 16 + hh) * 64 + dd)) * 2048 + sb + chunk * 8] =
          *(const bf16x8*)&smem[dl * 132 + chunk * 8];
    }
  }
}

// -------------------------------------------------------- flash attention
// attn12: LDS-BW test with the modern structure. Cycle audit of attn11:
// per CU per tile-round, 16 waves x 16 ds_read_b128 x 1KB = 256 KB LDS
// reads = 2300-3100 cyc at the 85-112 B/cyc LDS ceiling, vs 3800 cyc
// measured => LDS read BW is ~70-80% of wallclock. Every wave reads the
// SAME K/V tile; the only cut is more q per wave. R2/R3's regression of
// 2-q-set variants was confounded (P-LDS round-trip + per-tile vmcnt(0)
// drain, both since removed). attn12 = 2 q-sets on the attn10 ring:
//   256 thr / 4 waves x 32 q = 128 q/block, grid (16,16,2) = 2 blocks/CU
//   (indep. barriers cover each other), 8 waves/CU. Per-CU LDS traffic
//   per tile-round HALVES (each kf/vf read feeds 2 MFMAs). Ring-4,
//   counted vmcnt (4 loads/tile -> steady vmcnt(8), tail 4->0), loads
//   issued a full tile ahead (~2000 cyc >> 900 cyc HBM latency).
// Keeps: sigma-permuted K staging (sigma(r+32)=sigma(r)+32 since bit5
// fixed -> 2-row staging stays exact), register-P, ones-MFMA row-sum.
__global__ __launch_bounds__(256, 2)
void attn12(const u16* __restrict__ QN, const u16* __restrict__ KN,
            const u16* __restrict__ VT, u16* __restrict__ AO) {
  __shared__ u16 lK[4][64 * 64];
  __shared__ u16 lV[4][64 * 64];
  const int qt0 = blockIdx.x, h = blockIdx.y, b = blockIdx.z;
  const int t = threadIdx.x, lane = t & 63, w = t >> 6;
  const int quad = lane >> 4, l16 = lane & 15;
  const u16* Qg = QN + ((size_t)(b * 2048 + qt0 * 128)) * 1024 + h * 64;
  const u16* Kg = KN + ((size_t)b * 2048) * 1024 + h * 64;
  const u16* Vg = VT + ((size_t)((b * 16 + h) * 64)) * 2048;

  // staging rows: thread t covers chunk t (rows 0..31) and t+256 (rows 32..63)
  const int sr_r = t >> 3;                 // 0..31
  // sigma(r): bit4<-bit3, bit3<-bit2, bit2<-bit4 (bits 5,1,0 fixed)
  const int sg_r = (sr_r & 0x23) | ((sr_r & 8) << 1) | ((sr_r & 4) << 1) |
                   ((sr_r & 16) >> 2);
  const int sc_c = (t & 7) ^ (sr_r & 7);   // same for row+32 (r&7 unchanged)

  // Q fragments straight from global (pre-scaled by CSC in qkv_gemm)
  // qf[qs][ks]: q rows w*32 + qs*16 + l16
  bf16x8 qf[2][2];
#pragma unroll
  for (int qs = 0; qs < 2; ++qs)
#pragma unroll
    for (int ks = 0; ks < 2; ++ks)
      qf[qs][ks] = *(const bf16x8*)(Qg + (size_t)(w * 32 + qs * 16 + l16) * 1024 +
                                    ks * 32 + quad * 8);

  // bf16 1.0 x8 (A-operand of the ones-MFMA row-sum)
  const bf16x8 ones = {0x3F80, 0x3F80, 0x3F80, 0x3F80,
                       0x3F80, 0x3F80, 0x3F80, 0x3F80};

#define STAGE12(kb, buf)                                                      \
  do {                                                                        \
    async16(Kg + (size_t)((kb) + sg_r) * 1024 + sc_c * 8, &lK[buf][t * 8]);   \
    async16(Kg + (size_t)((kb) + sg_r + 32) * 1024 + sc_c * 8,                \
            &lK[buf][(t + 256) * 8]);                                         \
    async16(Vg + (size_t)sr_r * 2048 + (kb) + sc_c * 8, &lV[buf][t * 8]);     \
    async16(Vg + (size_t)(sr_r + 32) * 2048 + (kb) + sc_c * 8,                \
            &lV[buf][(t + 256) * 8]);                                         \
  } while (0)

  // prologue: stage tiles 0 and 1
  STAGE12(0, 0);
  STAGE12(64, 1);

  f32x4 o[2][4] = {};
  f32x4 ls0 = {}, ls1 = {};   // [0] = full row sum per q-set via ones-MFMA

  for (int kt = 0; kt < 32; ++kt) {
    if (kt + 2 < 32) {
      const int kb = (kt + 2) * 64;
      const int nb = (kt + 2) & 3;
      STAGE12(kb, nb);
    }
    // counted wait: tile kt's 4 loads landed; kt+1/kt+2's 8 may stay in flight
    if (kt < 30)       asm volatile("s_waitcnt vmcnt(8)" ::: "memory");
    else if (kt == 30) asm volatile("s_waitcnt vmcnt(4)" ::: "memory");
    else               asm volatile("s_waitcnt vmcnt(0)" ::: "memory");
    __builtin_amdgcn_s_barrier();
    __builtin_amdgcn_sched_barrier(0);

    const int cur = kt & 3;

    // ---- QK^T -> S^T (sigma-permuted rows), BOTH q-sets share kf reads
    f32x4 sc[2][4];
    __builtin_amdgcn_s_setprio(1);
#pragma unroll
    for (int st = 0; st < 4; ++st) {
      int row = st * 16 + l16;
      bf16x8 kf0 = *(const bf16x8*)&lK[cur][row * 64 + ((quad) ^ (row & 7)) * 8];
      bf16x8 kf1 = *(const bf16x8*)&lK[cur][row * 64 + ((4 + quad) ^ (row & 7)) * 8];
#pragma unroll
      for (int qs = 0; qs < 2; ++qs) {
        f32x4 z = {};
        sc[qs][st] = mfma16(kf0, qf[qs][0], z);
        sc[qs][st] = mfma16(kf1, qf[qs][1], sc[qs][st]);
      }
    }
    __builtin_amdgcn_s_setprio(0);

    // ---- p = exp2(s); pack into PV fragments (registers only)
    union { uint32_t uw[4]; bf16x8 v; } p00, p01, p10, p11;
#pragma unroll
    for (int st = 0; st < 2; ++st) {
      p00.uw[st * 2 + 0] = pk2bf(EXP2F(sc[0][st][0]), EXP2F(sc[0][st][1]));
      p00.uw[st * 2 + 1] = pk2bf(EXP2F(sc[0][st][2]), EXP2F(sc[0][st][3]));
      p01.uw[st * 2 + 0] = pk2bf(EXP2F(sc[0][2 + st][0]), EXP2F(sc[0][2 + st][1]));
      p01.uw[st * 2 + 1] = pk2bf(EXP2F(sc[0][2 + st][2]), EXP2F(sc[0][2 + st][3]));
      p10.uw[st * 2 + 0] = pk2bf(EXP2F(sc[1][st][0]), EXP2F(sc[1][st][1]));
      p10.uw[st * 2 + 1] = pk2bf(EXP2F(sc[1][st][2]), EXP2F(sc[1][st][3]));
      p11.uw[st * 2 + 0] = pk2bf(EXP2F(sc[1][2 + st][0]), EXP2F(sc[1][2 + st][1]));
      p11.uw[st * 2 + 1] = pk2bf(EXP2F(sc[1][2 + st][2]), EXP2F(sc[1][2 + st][3]));
    }

    // ---- PV: both q-sets share vf reads; row-sums on the MFMA pipe
    __builtin_amdgcn_s_setprio(1);
    ls0 = mfma16(ones, p00.v, ls0);
    ls0 = mfma16(ones, p01.v, ls0);
    ls1 = mfma16(ones, p10.v, ls1);
    ls1 = mfma16(ones, p11.v, ls1);
#pragma unroll
    for (int dt = 0; dt < 4; ++dt) {
      int row = dt * 16 + l16;
      bf16x8 vf0 = *(const bf16x8*)&lV[cur][row * 64 + ((quad) ^ (row & 7)) * 8];
      bf16x8 vf1 = *(const bf16x8*)&lV[cur][row * 64 + ((4 + quad) ^ (row & 7)) * 8];
      o[0][dt] = mfma16(vf0, p00.v, o[0][dt]);
      o[0][dt] = mfma16(vf1, p01.v, o[0][dt]);
      o[1][dt] = mfma16(vf0, p10.v, o[1][dt]);
      o[1][dt] = mfma16(vf1, p11.v, o[1][dt]);
    }
    __builtin_amdgcn_s_setprio(0);
  }
#undef STAGE12

  // ---- epilogue: O^T/l -> AO [b][s][h*64+d] bf16 (4 consecutive d per lane)
  float inv0 = 1.0f / ls0[0];
  float inv1 = 1.0f / ls1[0];
#pragma unroll
  for (int qs = 0; qs < 2; ++qs) {
    float inv = qs ? inv1 : inv0;
    int qglob = qt0 * 128 + w * 32 + qs * 16 + l16;
    size_t base = ((size_t)(b * 2048 + qglob)) * 1024 + h * 64;
#pragma unroll
    for (int dt = 0; dt < 4; ++dt) {
      ushort4 pk;
      pk.x = f2bf(o[qs][dt][0] * inv);
      pk.y = f2bf(o[qs][dt][1] * inv);
      pk.z = f2bf(o[qs][dt][2] * inv);
      pk.w = f2bf(o[qs][dt][3] * inv);
      *(ushort4*)&AO[base + dt * 16 + quad * 4] = pk;
    }
  }
}

// ------------------------------------------------------- output projection
// 128m x 64n tiles, BK=64, 512 blocks, XCD swizzle (m_tile = T&31).
// Normal orientation; scalar f32 stores = 64B runs (R3-style, known-good).
__global__ __launch_bounds__(256, 2)
void oproj_gemm(const u16* __restrict__ AO, const u16* __restrict__ Bt,
                const float* __restrict__ bias, float* __restrict__ out) {
  __shared__ u16 lA[128 * 64];
  __shared__ u16 lB[64 * 64];
  const int T = blockIdx.x;
  const int m0 = (T & 31) * 128, n0 = (T >> 5) * 64;
  const int t = threadIdx.x, lane = t & 63, w = t >> 6;
  const int quad = lane >> 4, l16 = lane & 15;
  const int wm = (w & 1) * 64, wn = (w >> 1) * 32;

  f32x4 acc[4][2] = {};
  for (int kt = 0; kt < 16; ++kt) {
    const int k0 = kt * 64;
#pragma unroll
    for (int it = 0; it < 4; ++it) {
      int i = it * 256 + t;
      int r = i >> 3, cc = i & 7, c = cc ^ (r & 7);
      async16(AO + (size_t)(m0 + r) * 1024 + k0 + c * 8, &lA[i * 8]);
    }
#pragma unroll
    for (int it = 0; it < 2; ++it) {
      int i = it * 256 + t;
      int r = i >> 3, cc = i & 7, c = cc ^ (r & 7);
      async16(Bt + (size_t)(n0 + r) * 1024 + k0 + c * 8, &lB[i * 8]);
    }
    __syncthreads();
#pragma unroll
    for (int ks = 0; ks < 2; ++ks) {
      bf16x8 af[4], bfr[2];
#pragma unroll
      for (int rt = 0; rt < 4; ++rt) {
        int row = wm + rt * 16 + l16;
        af[rt] = *(const bf16x8*)&lA[row * 64 + ((ks * 4 + quad) ^ (row & 7)) * 8];
      }
#pragma unroll
      for (int ct = 0; ct < 2; ++ct) {
        int row = wn + ct * 16 + l16;
        bfr[ct] = *(const bf16x8*)&lB[row * 64 + ((ks * 4 + quad) ^ (row & 7)) * 8];
      }
#pragma unroll
      for (int rt = 0; rt < 4; ++rt)
#pragma unroll
        for (int ct = 0; ct < 2; ++ct)
          acc[rt][ct] = mfma16(af[rt], bfr[ct], acc[rt][ct]);
    }
    __syncthreads();
  }

#pragma unroll
  for (int ct = 0; ct < 2; ++ct) {
    int ncol = n0 + wn + ct * 16 + l16;
    float bvv = bias[ncol];
#pragma unroll
    for (int rt = 0; rt < 4; ++rt)
#pragma unroll
      for (int r = 0; r < 4; ++r) {
        int m = m0 + wm + rt * 16 + quad * 4 + r;
        out[(size_t)m * 1024 + ncol] = acc[rt][ct][r] + bvv;
      }
  }
}

// ------------------------------------------------------------------ launch
extern "C" void kernel_launch(void* const* d_in, const int* in_sizes, int n_in,
                              void* d_out, int out_size, void* d_ws, size_t ws_size,
                              hipStream_t stream) {
  const float* query = (const float*)d_in[0];
  const float* key   = (const float*)d_in[1];
  const float* value = (const float*)d_in[2];
  const float* Wq = (const float*)d_in[3];
  const float* bq = (const float*)d_in[4];
  const float* Wk = (const float*)d_in[5];
  const float* bk = (const float*)d_in[6];
  const float* Wv = (const float*)d_in[7];
  const float* bv = (const float*)d_in[8];
  const float* Wo = (const float*)d_in[9];
  const float* bo = (const float*)d_in[10];
  float* out = (float*)d_out;

  // workspace layout (u16 elements): total 28M u16 = 56 MB
  u16* WT = (u16*)d_ws;              // 4 x 1M  (Wq_t, Wk_t, Wv_t, Wo_t)
  u16* QN = WT + 4 * 1048576;        // 4M  natural [b,s,1024] (pre-scaled by CSC)
  u16* KN = QN + 4194304;            // 4M  natural [b,s,1024]
  u16* VT = KN + 4194304;            // 4M  [b,h,d,s]
  u16* XB = VT + 4194304;            // 3 x 4M bf16 copies of q,k,v
  u16* AO = XB;                      // attn out aliases XB (dead by then)

  convx<<<dim3(4096, 3), 256, 0, stream>>>(query, key, value, XB);
  transw<<<dim3(16, 16, 4), 256, 0, stream>>>(Wq, Wk, Wv, Wo, WT);
  qkv_gemm<<<dim3(256, 3), 256, 0, stream>>>(XB, WT, bq, bk, bv, QN, KN, VT);
  attn12<<<dim3(16, 16, 2), 256, 0, stream>>>(QN, KN, VT, AO);
  oproj_gemm<<<dim3(512), 256, 0, stream>>>(AO, WT + 3 * 1048576, bo, out);
}